// Round 12
// baseline (249.523 us; speedup 1.0000x reference)
//
#include <hip/hip_runtime.h>

#define B_SZ 4096
#define S_SZ 128
#define XD 5
#define EH 128
#define DH 256
#define DSTEPS 10

typedef short v8s __attribute__((ext_vector_type(8)));
typedef float v4f __attribute__((ext_vector_type(4)));

__device__ __forceinline__ float bf2f(unsigned short u) {
    union { unsigned int i; float f; } v; v.i = ((unsigned int)u) << 16; return v.f;
}
__device__ __forceinline__ unsigned short f2bf(float f) {
    union { float f; unsigned int i; } v; v.f = f;
    unsigned int x = v.i;
    return (unsigned short)((x + 0x7FFFu + ((x >> 16) & 1u)) >> 16);
}
__device__ __forceinline__ float fexp2(float x) { return __builtin_amdgcn_exp2f(x); }
__device__ __forceinline__ float frcp(float x) { return __builtin_amdgcn_rcpf(x); }
// pack 2 f32 -> 1 u32 of 2 bf16 (low word = first operand). HW-verified.
__device__ __forceinline__ unsigned int cvt2bf(float lo, float hi) {
    unsigned int r;
    asm("v_cvt_pk_bf16_f32 %0, %1, %2" : "=v"(r) : "v"(lo), "v"(hi));
    return r;
}

#define SC_S (-1.44269504088896f)   // sigmoid: rcp(1+exp2(SC_S*x))
#define SC_T ( 2.88539008177793f)   // tanh:    1-2*rcp(exp2(SC_T*x)+1)

// ---------------------------------------------------------------- fused enc+dec v3
// SINGLE kernel: 256 blocks x 1024 thr (16 waves), 1 block/CU (144 KB LDS).
// Changes vs R10:
//  - prep_kernel DELETED. R9/R10 both carried a constant 63.5us residual
//    (bench dur - fused profiled) that appeared with prep; the R9->R10
//    bench delta tracked the fused delta exactly. All weight conversion
//    now happens in-kernel.
//  - dec fB loaded fp32->scaled-bf16 DIRECTLY INTO REGISTERS. R10's
//    VGPR_Count=64 + WRITE 18.4MB showed the compiler rematerialized the
//    plain bf16 global loads inside the step loop (L2-latency x24/lane/step)
//    instead of keeping 96 regs resident. The convert sequence (mul+round+
//    pack) is too expensive to remat -> forces true residency (~125 regs,
//    fits the 16-wave/CU 128-reg cap).
//  - workspace unused; gi B-frags + wy come from dWih fp32 directly.
__global__ __launch_bounds__(1024)
void fused_kernel(
    const float* __restrict__ x,       // [B][S][5] fp32
    const float* __restrict__ Wih32,   // [384][5] fp32
    const float* __restrict__ Whh32,   // [384][128] fp32
    const float* __restrict__ bih,     // [384] fp32
    const float* __restrict__ bhh,     // [384] fp32
    const float* __restrict__ dWih,    // [768][129] fp32
    const float* __restrict__ dWhh,    // [768][256] fp32
    const float* __restrict__ dbih,    // [768] fp32
    const float* __restrict__ dbhh,    // [768] fp32
    const float* __restrict__ y,       // [B][128] fp32
    const float* __restrict__ linW,    // [4][256] fp32
    const float* __restrict__ linb,    // [4] fp32
    float* __restrict__ out)           // [B][S][4] fp32
{
    // uni: enc = xs[128][16][8] (32 KB); dec = const slab 1024*29 f32 (116 KB)
    __shared__ __align__(16) char uni[118784];
    __shared__ unsigned short hb[2][16][136];      // 8.5 KB (h_128 -> dec gi)
    __shared__ __align__(16) unsigned short zpad[8];
    __shared__ unsigned short hshf[32 * 16 * 8];   // 8 KB dec h state (frag)
    __shared__ unsigned short lwf[32 * 16 * 8];    // 8 KB linW (frag)
    __shared__ float ysh[16][DSTEPS];              // 640 B y slab

    const int tid = threadIdx.x;
    const int bid = blockIdx.x;
    const int wv = tid >> 6;        // 0..15
    const int lane = tid & 63;
    const int n = lane & 15;
    const int kg = lane >> 4;
    const int r0 = bid * 16;

    // ================= PHASE 1: encoder (v4 logic, waves 0-7) ================
    {
        auto xs = (unsigned short (*)[16][8])uni;   // [128][16][8]

        for (int i = tid; i < 2 * 16 * 136; i += 1024) ((unsigned short*)hb)[i] = 0;
        if (tid < 8) zpad[tid] = 0;
        for (int i = tid; i < 16 * S_SZ * 8; i += 1024) {
            int m = i >> 10;
            int rem = i & 1023;
            int t = rem >> 3;
            int j = rem & 7;
            unsigned short v = 0;
            if (j < XD) v = f2bf(x[(size_t)(r0 + m) * (S_SZ * XD) + t * XD + j]);
            else if (j == XD) v = 0x3F80;          // constant-1 bias carrier
            xs[t][m][j] = v;
        }

        const int colw = wv * 16 + n;              // valid for wv<8
        v8s fw[3][4];
        v8s fx[3];
        float bhn = 0.f;
        if (wv < 8) {
            #pragma unroll
            for (int g = 0; g < 3; ++g) {
                const float sc = (g < 2) ? SC_S : SC_T;
                const int gcol = g * EH + colw;
                #pragma unroll
                for (int kt = 0; kt < 4; ++kt) {
                    const float* p = &Whh32[(size_t)gcol * EH + kt * 32 + kg * 8];
                    float4 lo = *(const float4*)p;
                    float4 hi = *(const float4*)(p + 4);
                    v8s f;
                    f[0] = (short)f2bf(sc * lo.x); f[1] = (short)f2bf(sc * lo.y);
                    f[2] = (short)f2bf(sc * lo.z); f[3] = (short)f2bf(sc * lo.w);
                    f[4] = (short)f2bf(sc * hi.x); f[5] = (short)f2bf(sc * hi.y);
                    f[6] = (short)f2bf(sc * hi.z); f[7] = (short)f2bf(sc * hi.w);
                    fw[g][kt] = f;
                }
                v8s t = {0, 0, 0, 0, 0, 0, 0, 0};
                if (kg == 0) {
                    const float* p = &Wih32[gcol * XD];
                    #pragma unroll
                    for (int j = 0; j < XD; ++j) t[j] = (short)f2bf(sc * p[j]);
                    float b = (g < 2) ? (sc * (bih[gcol] + bhh[gcol]))
                                      : (sc * bih[gcol]);
                    t[XD] = (short)f2bf(b);
                }
                fx[g] = t;
            }
            bhn = SC_T * bhh[2 * EH + colw];
        }

        const v4f vzero = {0.f, 0.f, 0.f, 0.f};
        float hst[4] = {0.f, 0.f, 0.f, 0.f};
        __syncthreads();

        #pragma unroll 2
        for (int t = 0; t < S_SZ; ++t) {
            const int p = t & 1;
            if (wv < 8) {
                v8s a[4];
                #pragma unroll
                for (int kt = 0; kt < 4; ++kt)
                    a[kt] = *(const v8s*)&hb[p][n][kt * 32 + kg * 8];
                const unsigned short* xsrc = (kg == 0) ? &xs[t][n][0] : &zpad[0];
                v8s ax = *(const v8s*)xsrc;

                v4f accr  = __builtin_amdgcn_mfma_f32_16x16x32_bf16(a[0], fw[0][0], vzero, 0, 0, 0);
                v4f accz  = __builtin_amdgcn_mfma_f32_16x16x32_bf16(a[0], fw[1][0], vzero, 0, 0, 0);
                v4f acchn = __builtin_amdgcn_mfma_f32_16x16x32_bf16(a[0], fw[2][0], vzero, 0, 0, 0);
                #pragma unroll
                for (int kt = 1; kt < 4; ++kt) {
                    accr  = __builtin_amdgcn_mfma_f32_16x16x32_bf16(a[kt], fw[0][kt], accr, 0, 0, 0);
                    accz  = __builtin_amdgcn_mfma_f32_16x16x32_bf16(a[kt], fw[1][kt], accz, 0, 0, 0);
                    acchn = __builtin_amdgcn_mfma_f32_16x16x32_bf16(a[kt], fw[2][kt], acchn, 0, 0, 0);
                }
                accr = __builtin_amdgcn_mfma_f32_16x16x32_bf16(ax, fx[0], accr, 0, 0, 0);
                accz = __builtin_amdgcn_mfma_f32_16x16x32_bf16(ax, fx[1], accz, 0, 0, 0);
                v4f accin = __builtin_amdgcn_mfma_f32_16x16x32_bf16(ax, fx[2], vzero, 0, 0, 0);

                float hnew[4];
                #pragma unroll
                for (int e = 0; e < 4; ++e) {
                    float r  = frcp(1.f + fexp2(accr[e]));
                    float z  = frcp(1.f + fexp2(accz[e]));
                    float nn = 1.f - 2.f * frcp(fexp2(accin[e] + r * (acchn[e] + bhn)) + 1.f);
                    float h  = nn + z * (hst[e] - nn);
                    hst[e] = h;
                    hnew[e] = h;
                }
                const unsigned int pk01 = cvt2bf(hnew[0], hnew[1]);
                const unsigned int pk23 = cvt2bf(hnew[2], hnew[3]);
                hb[1 - p][kg * 4 + 0][colw] = (unsigned short)(pk01 & 0xFFFFu);
                hb[1 - p][kg * 4 + 1][colw] = (unsigned short)(pk01 >> 16);
                hb[1 - p][kg * 4 + 2][colw] = (unsigned short)(pk23 & 0xFFFFu);
                hb[1 - p][kg * 4 + 3][colw] = (unsigned short)(pk23 >> 16);
            }
            __syncthreads();
        }
        // h_128 lives in hb[0][row][col].
    }

    // ================= PHASE 2: decoder (16 waves x 16 cols/gate) ============
    {
        const int w = wv;
        const int colb = w * 16;                   // this wave's 16 cols (per gate)
        const int rb = r0;
        float* gwsh = (float*)uni;                 // [1024*29] f32 const slab

        // stage linW into frag layout (first 512 threads only)
        if (tid < 512) {
            int col = tid >> 5, kgrp = tid & 31;
            unsigned short v8[8];
            #pragma unroll
            for (int j = 0; j < 8; ++j)
                v8[j] = (col < 4) ? f2bf(linW[col * 256 + kgrp * 8 + j]) : (unsigned short)0;
            *(uint4*)&lwf[(kgrp * 16 + col) * 8] = *(uint4*)v8;
        }
        // stage y slab
        if (tid < 16 * DSTEPS) {
            int row = tid / DSTEPS, tt = tid - row * DSTEPS;
            ysh[row][tt] = y[(size_t)(rb + row) * S_SZ + tt];
        }
        // h0 = 1
        for (int i = tid; i < 32 * 16 * 8; i += 1024) hshf[i] = 0x3F80;

        // resident Whh: fp32 -> scaled bf16 in REGISTERS (3 gates x 8 kt = 96
        // VGPRs). The convert chain defeats rematerialization -> stays resident.
        v8s fB[3][8];
        #pragma unroll
        for (int g = 0; g < 3; ++g) {
            const float sc = (g < 2) ? SC_S : SC_T;
            const float* wrow = &dWhh[(size_t)(g * DH + colb + n) * DH];
            #pragma unroll
            for (int kt = 0; kt < 8; ++kt) {
                const float* p = wrow + kt * 32 + kg * 8;
                float4 lo = *(const float4*)p;
                float4 hi = *(const float4*)(p + 4);
                v8s f;
                f[0] = (short)f2bf(sc * lo.x); f[1] = (short)f2bf(sc * lo.y);
                f[2] = (short)f2bf(sc * lo.z); f[3] = (short)f2bf(sc * lo.w);
                f[4] = (short)f2bf(sc * hi.x); f[5] = (short)f2bf(sc * hi.y);
                f[6] = (short)f2bf(sc * hi.z); f[7] = (short)f2bf(sc * hi.w);
                fB[g][kt] = f;
            }
        }

        // gi = (Wih . h128^T) via swapped mfma: lane (n,kg) elem e ->
        // (gatecol colb+kg*4+e, batchrow n). B-frags from dWih fp32 (scalar
        // loads: row stride 129 f32 -> only 4B-aligned).
        const v4f vzero = {0.f, 0.f, 0.f, 0.f};
        v4f gi[3];
        #pragma unroll
        for (int g = 0; g < 3; ++g) gi[g] = vzero;

        #pragma unroll
        for (int kt = 0; kt < 4; ++kt) {
            v8s actex = *(const v8s*)&hb[0][n][kt * 32 + kg * 8];
            #pragma unroll
            for (int g = 0; g < 3; ++g) {
                const float sc = (g < 2) ? SC_S : SC_T;
                const float* p = &dWih[(size_t)(g * DH + colb + n) * 129 + kt * 32 + kg * 8];
                v8s bw;
                #pragma unroll
                for (int j = 0; j < 8; ++j) bw[j] = (short)f2bf(sc * p[j]);
                gi[g] = __builtin_amdgcn_mfma_f32_16x16x32_bf16(bw, actex, gi[g], 0, 0, 0);
            }
        }

        // slab layout per thread (stride 29): [0..11] gi, [12..23] wy, [24..27] bN
        #pragma unroll
        for (int g = 0; g < 3; ++g) {
            const float sc = (g < 2) ? SC_S : SC_T;
            #pragma unroll
            for (int e = 0; e < 4; ++e) {
                const int gcol = g * DH + colb + kg * 4 + e;
                gi[g][e] += sc * (dbih[gcol] + ((g < 2) ? dbhh[gcol] : 0.f));
                gwsh[tid * 29 + 12 + g * 4 + e] = sc * dWih[(size_t)gcol * 129 + 128];
            }
            *(v4f*)&gwsh[tid * 29 + g * 4] = gi[g];
        }
        #pragma unroll
        for (int e = 0; e < 4; ++e)
            gwsh[tid * 29 + 24 + e] = SC_T * dbhh[2 * DH + colb + kg * 4 + e];

        float hprev[4] = {1.f, 1.f, 1.f, 1.f};
        __syncthreads();

        for (int t = 0; t < DSTEPS; ++t) {
            const float yv = ysh[n][t];

            v4f ar = vzero, az = vzero, an = vzero;
            #pragma unroll
            for (int kt = 0; kt < 8; ++kt) {
                v8s a = *(const v8s*)&hshf[((kt * 4 + kg) * 16 + n) * 8];
                ar = __builtin_amdgcn_mfma_f32_16x16x32_bf16(fB[0][kt], a, ar, 0, 0, 0);
                az = __builtin_amdgcn_mfma_f32_16x16x32_bf16(fB[1][kt], a, az, 0, 0, 0);
                an = __builtin_amdgcn_mfma_f32_16x16x32_bf16(fB[2][kt], a, an, 0, 0, 0);
            }
            __syncthreads();   // all reads of h_t complete

            float hh[4];
            #pragma unroll
            for (int e = 0; e < 4; ++e) {
                const float giR = gwsh[tid * 29 + 0 + e];
                const float giZ = gwsh[tid * 29 + 4 + e];
                const float giN = gwsh[tid * 29 + 8 + e];
                const float wyR = gwsh[tid * 29 + 12 + e];
                const float wyZ = gwsh[tid * 29 + 16 + e];
                const float wyN = gwsh[tid * 29 + 20 + e];
                const float bN  = gwsh[tid * 29 + 24 + e];
                float r  = frcp(1.f + fexp2(giR + yv * wyR + ar[e]));
                float z  = frcp(1.f + fexp2(giZ + yv * wyZ + az[e]));
                float nn = 1.f - 2.f * frcp(
                    fexp2(giN + yv * wyN + r * (an[e] + bN)) + 1.f);
                float h  = nn + z * (hprev[e] - nn);
                hprev[e] = h;
                hh[e] = h;
            }
            const unsigned int p01 = cvt2bf(hh[0], hh[1]);
            const unsigned int p23 = cvt2bf(hh[2], hh[3]);
            const int base = colb + kg * 4;        // 4 consecutive cols
            const int idx = (((base >> 3) * 16) + n) * 8 + (base & 7);
            *(uint2*)&hshf[idx] = (uint2){p01, p23};
            __syncthreads();   // h_{t+1} visible

            if (w == t) {      // out-proj, rotated across waves (t<10<16)
                v4f o4 = vzero;
                #pragma unroll
                for (int kt = 0; kt < 8; ++kt) {
                    v8s a = *(const v8s*)&hshf[((kt * 4 + kg) * 16 + n) * 8];
                    v8s b = *(const v8s*)&lwf[((kt * 4 + kg) * 16 + n) * 8];
                    o4 = __builtin_amdgcn_mfma_f32_16x16x32_bf16(b, a, o4, 0, 0, 0);
                }
                if (kg == 0) {
                    const float4 lb4 = *(const float4*)linb;
                    float4 ov = {o4[0] + lb4.x, o4[1] + lb4.y, o4[2] + lb4.z, o4[3] + lb4.w};
                    *(float4*)&out[(size_t)(rb + n) * (S_SZ * 4) + t * 4] = ov;
                }
            }
        }

        // tail pad: out[:, 10:, :] = 1.0
        for (int j = tid; j < 16 * 512; j += 1024) {
            int row = j >> 9, c = j & 511;
            if (c >= DSTEPS * 4) out[(size_t)(rb + row) * 512 + c] = 1.0f;
        }
    }
}

// ---------------------------------------------------------------- launch
extern "C" void kernel_launch(void* const* d_in, const int* in_sizes, int n_in,
                              void* d_out, int out_size, void* d_ws, size_t ws_size,
                              hipStream_t stream)
{
    const float* x    = (const float*)d_in[0];
    const float* y    = (const float*)d_in[1];
    const float* eWih = (const float*)d_in[2];
    const float* eWhh = (const float*)d_in[3];
    const float* ebih = (const float*)d_in[4];
    const float* ebhh = (const float*)d_in[5];
    const float* dWih = (const float*)d_in[6];
    const float* dWhh = (const float*)d_in[7];
    const float* dbih = (const float*)d_in[8];
    const float* dbhh = (const float*)d_in[9];
    const float* linW = (const float*)d_in[10];
    const float* linb = (const float*)d_in[11];
    float* out = (float*)d_out;

    (void)d_ws; (void)ws_size;   // workspace unused: all conversion in-kernel

    fused_kernel<<<256, 1024, 0, stream>>>(x, eWih, eWhh, ebih, ebhh,
                                           dWih, dWhh, dbih, dbhh, y,
                                           linW, linb, out);
}